// Round 1
// baseline (290.642 us; speedup 1.0000x reference)
//
#include <hip/hip_runtime.h>
#include <hip/hip_bf16.h>

typedef unsigned short u16;
typedef unsigned int u32;
typedef __attribute__((ext_vector_type(8))) __bf16 bf16x8;
typedef __attribute__((ext_vector_type(4))) float f32x4;
typedef __attribute__((ext_vector_type(8))) short short8;

#define EPSF 2.220446049250313e-16f

static_assert(sizeof(bf16x8) == 16, "bf16x8 must be 16B");

// ---------- helpers ----------
__device__ __forceinline__ u16 f2bf(float f) {
    u32 u = __float_as_uint(f);
    return (u16)((u + 0x7FFFu + ((u >> 16) & 1u)) >> 16);  // RNE
}

// order-preserving float<->uint key (for atomicMax on signed floats)
__device__ __forceinline__ u32 f2key(float f) {
    u32 u = __float_as_uint(f);
    return (u & 0x80000000u) ? ~u : (u | 0x80000000u);
}
__device__ __forceinline__ float key2f(u32 k) {
    u32 u = (k & 0x80000000u) ? (k & 0x7FFFFFFFu) : ~k;
    return __uint_as_float(u);
}

__device__ __forceinline__ void gll16(const void* g, void* l) {
    __builtin_amdgcn_global_load_lds(
        (const __attribute__((address_space(1))) unsigned int*)g,
        (__attribute__((address_space(3))) unsigned int*)l, 16, 0, 0);
}

// ---------- kernel 1: PONO center + L2 normalize + transposed bf16 write ----------
// grid: 256 blocks (b = blk>>6, 64 pixels each), 256 threads
__global__ __launch_bounds__(256) void prep_kernel(
    const float* __restrict__ X, const float* __restrict__ Y,
    u16* __restrict__ XnT, u16* __restrict__ YnT,
    u32* __restrict__ smaxkey, float* __restrict__ Ssum)
{
    const int b  = blockIdx.x >> 6;
    const int p0 = (blockIdx.x & 63) << 6;
    const int t  = threadIdx.x;
    const int w  = t >> 6;     // channel quarter (wave id)
    const int ln = t & 63;     // pixel (passes 1-2)
    const size_t base = (size_t)b * 256 * 4096;

    __shared__ float part[8][64];
    __shared__ float meanL[64], rxL[64], ryL[64];

    // init per-row state (ws is poisoned each call)
    if (t < 64) {
        smaxkey[(size_t)b * 4096 + p0 + t] = 0x3FFFFFFFu;  // key(-2.0f)
        Ssum[(size_t)b * 4096 + p0 + t] = 0.0f;
    }

    // pass 1: mean over channels of Y (coalesced: lane = pixel)
    float sy = 0.f;
    #pragma unroll 4
    for (int k = 0; k < 64; ++k)
        sy += Y[base + (size_t)(w * 64 + k) * 4096 + p0 + ln];
    part[w][ln] = sy;
    __syncthreads();
    const float mean =
        (part[0][ln] + part[1][ln] + part[2][ln] + part[3][ln]) * (1.f / 256.f);
    __syncthreads();

    // pass 2: centered sum-of-squares for X and Y
    float ssx = 0.f, ssy = 0.f;
    #pragma unroll 4
    for (int k = 0; k < 64; ++k) {
        size_t off = base + (size_t)(w * 64 + k) * 4096 + p0 + ln;
        float dx = X[off] - mean; ssx += dx * dx;
        float dy = Y[off] - mean; ssy += dy * dy;
    }
    part[w][ln] = ssx;
    part[4 + w][ln] = ssy;
    __syncthreads();
    if (w == 0) {
        float sx = part[0][ln] + part[1][ln] + part[2][ln] + part[3][ln];
        float sy2 = part[4][ln] + part[5][ln] + part[6][ln] + part[7][ln];
        meanL[ln] = mean;
        rxL[ln] = 1.f / (sqrtf(sx) + EPSF);
        ryL[ln] = 1.f / (sqrtf(sy2) + EPSF);
    }
    __syncthreads();

    // pass 3: normalize + write transposed [p][c] bf16, coalesced 16B stores
    const int oct  = t & 31;   // channel octet: c0 = oct*8
    const int psub = t >> 5;   // 0..7
    #pragma unroll
    for (int pp = 0; pp < 8; ++pp) {
        int p = pp * 8 + psub;
        float m = meanL[p], rxv = rxL[p], ryv = ryL[p];
        short8 hx, hy;
        #pragma unroll
        for (int k = 0; k < 8; ++k) {
            int c = oct * 8 + k;
            size_t off = base + (size_t)c * 4096 + p0 + p;
            hx[k] = (short)f2bf((X[off] - m) * rxv);
            hy[k] = (short)f2bf((Y[off] - m) * ryv);
        }
        size_t ob = ((size_t)b * 4096 + p0 + p) * 256 + oct * 8;
        *(short8*)(XnT + ob) = hx;
        *(short8*)(YnT + ob) = hy;
    }
}

// ---------- kernels 2/3: fused GEMM + rowmax (PASS=0) / rowsum-exp (PASS=1) ----------
// tile 128x128, BK=64, 4 waves (2x2), 16x16x32 bf16 MFMA, m97-style staging
template <int PASS>
__global__ __launch_bounds__(256) void cx_pass(
    const u16* __restrict__ XnT, const u16* __restrict__ YnT,
    u32* __restrict__ smaxkey, float* __restrict__ Ssum)
{
    __shared__ u16 As[128 * 64];   // 16 KB, XOR-swizzled rows
    __shared__ u16 Bs[128 * 64];
    __shared__ float smx[128];

    const int t = threadIdx.x;
    const int w = t >> 6;
    const int l = t & 63;

    // XCD-aware swizzle: batch b -> XCDs {2b, 2b+1}; operands (4MB bf16) L2-fit
    const int id   = blockIdx.x;
    const int xcd  = id & 7;
    const int slot = id >> 3;                 // 0..511
    const int b    = xcd >> 1;
    const int tile = ((xcd & 1) << 9) | slot; // 0..1023
    const int it = tile >> 5, jt = tile & 31;
    const int i0 = it << 7, j0 = jt << 7;

    const u16* Ab = XnT + ((size_t)b * 4096 + i0) * 256;
    const u16* Bb = YnT + ((size_t)b * 4096 + j0) * 256;

    if (PASS == 1 && t < 128)
        smx[t] = key2f(smaxkey[(size_t)b * 4096 + i0 + t]);

    const int wr = w >> 1, wc = w & 1;
    const int l8 = l & 7, ld8 = l >> 3;
    const int srcChunk = (l8 ^ ld8) << 3;  // inverse-swizzled source chunk (elems)

    f32x4 acc[4][4] = {};

    #pragma unroll
    for (int kt = 0; kt < 4; ++kt) {
        // stage A,B tiles: 4 waves x 4 chunks x 1KB each, linear LDS dest,
        // pre-swizzled global source (involution: chunk ^ (row&7))
        #pragma unroll
        for (int q = 0; q < 4; ++q) {
            const int rbase = (w * 4 + q) * 8;
            const int row = rbase + ld8;
            gll16(Ab + (size_t)row * 256 + kt * 64 + srcChunk, &As[rbase * 64]);
            gll16(Bb + (size_t)row * 256 + kt * 64 + srcChunk, &Bs[rbase * 64]);
        }
        __syncthreads();
        #pragma unroll
        for (int ks = 0; ks < 2; ++ks) {
            const int kb = (ks * 32 + (l >> 4) * 8) * 2;  // frag byte offset in row
            bf16x8 av[4], bv[4];
            #pragma unroll
            for (int f = 0; f < 4; ++f) {
                int ra = wr * 64 + f * 16 + (l & 15);
                av[f] = *(const bf16x8*)((const char*)As + ra * 128 + (kb ^ ((ra & 7) << 4)));
                int rb = wc * 64 + f * 16 + (l & 15);
                bv[f] = *(const bf16x8*)((const char*)Bs + rb * 128 + (kb ^ ((rb & 7) << 4)));
            }
            #pragma unroll
            for (int fr = 0; fr < 4; ++fr)
                #pragma unroll
                for (int fc = 0; fc < 4; ++fc)
                    acc[fr][fc] = __builtin_amdgcn_mfma_f32_16x16x32_bf16(
                        av[fr], bv[fc], acc[fr][fc], 0, 0, 0);
        }
        __syncthreads();
    }

    // epilogue: C/D map col=l&15, row=(l>>4)*4+r (verified m89/m91)
    const int g = l >> 4;
    #pragma unroll
    for (int fr = 0; fr < 4; ++fr) {
        #pragma unroll
        for (int r = 0; r < 4; ++r) {
            const int row = wr * 64 + fr * 16 + g * 4 + r;
            if (PASS == 0) {
                float m = fmaxf(fmaxf(acc[fr][0][r], acc[fr][1][r]),
                                fmaxf(acc[fr][2][r], acc[fr][3][r]));
                m = fmaxf(m, __shfl_xor(m, 1, 64));
                m = fmaxf(m, __shfl_xor(m, 2, 64));
                m = fmaxf(m, __shfl_xor(m, 4, 64));
                m = fmaxf(m, __shfl_xor(m, 8, 64));
                if ((l & 15) == 0)
                    atomicMax(&smaxkey[(size_t)b * 4096 + i0 + row], f2key(m));
            } else {
                float mrow = smx[row];
                float itau = 1.0f / (0.1f * (1.001f - mrow));
                float s = __expf((acc[fr][0][r] - mrow) * itau)
                        + __expf((acc[fr][1][r] - mrow) * itau)
                        + __expf((acc[fr][2][r] - mrow) * itau)
                        + __expf((acc[fr][3][r] - mrow) * itau);
                s += __shfl_xor(s, 1, 64);
                s += __shfl_xor(s, 2, 64);
                s += __shfl_xor(s, 4, 64);
                s += __shfl_xor(s, 8, 64);
                if ((l & 15) == 0)
                    atomicAdd(&Ssum[(size_t)b * 4096 + i0 + row], s);
            }
        }
    }
}

// ---------- kernel 4: final reduction ----------
__global__ __launch_bounds__(256) void final_kernel(
    const float* __restrict__ Ssum, float* __restrict__ out)
{
    __shared__ float red[4];
    const int t = threadIdx.x;
    float loss = 0.f;
    for (int b = 0; b < 4; ++b) {
        float s = 0.f;
        for (int i = t; i < 4096; i += 256)
            s += 1.0f / Ssum[(size_t)b * 4096 + i];
        #pragma unroll
        for (int d = 1; d <= 32; d <<= 1) s += __shfl_xor(s, d, 64);
        if ((t & 63) == 0) red[t >> 6] = s;
        __syncthreads();
        if (t == 0) {
            float tot = red[0] + red[1] + red[2] + red[3];
            loss += -logf(tot * (1.f / 4096.f));
        }
        __syncthreads();
    }
    if (t == 0) out[0] = loss * 0.25f;
}

extern "C" void kernel_launch(void* const* d_in, const int* in_sizes, int n_in,
                              void* d_out, int out_size, void* d_ws, size_t ws_size,
                              hipStream_t stream)
{
    const float* X = (const float*)d_in[0];
    const float* Y = (const float*)d_in[1];
    char* ws = (char*)d_ws;
    u16* XnT = (u16*)(ws);                              // 8 MB
    u16* YnT = (u16*)(ws + (8u << 20));                 // 8 MB
    u32* smaxkey = (u32*)(ws + (16u << 20));            // 64 KB
    float* Ssum = (float*)(ws + (16u << 20) + (64u << 10));  // 64 KB
    float* out = (float*)d_out;

    hipLaunchKernelGGL(prep_kernel, dim3(256), dim3(256), 0, stream,
                       X, Y, XnT, YnT, smaxkey, Ssum);
    hipLaunchKernelGGL((cx_pass<0>), dim3(4096), dim3(256), 0, stream,
                       XnT, YnT, smaxkey, Ssum);
    hipLaunchKernelGGL((cx_pass<1>), dim3(4096), dim3(256), 0, stream,
                       XnT, YnT, smaxkey, Ssum);
    hipLaunchKernelGGL(final_kernel, dim3(1), dim3(256), 0, stream, Ssum, out);
}

// Round 2
// 220.078 us; speedup vs baseline: 1.3206x; 1.3206x over previous
//
#include <hip/hip_runtime.h>
#include <hip/hip_bf16.h>

typedef unsigned short u16;
typedef unsigned int u32;
typedef __attribute__((ext_vector_type(8))) __bf16 bf16x8;
typedef __attribute__((ext_vector_type(4))) float f32x4;
typedef __attribute__((ext_vector_type(8))) short short8;

#define EPSF 2.220446049250313e-16f

static_assert(sizeof(bf16x8) == 16, "bf16x8 must be 16B");

// ---------- helpers ----------
__device__ __forceinline__ u16 f2bf(float f) {
    u32 u = __float_as_uint(f);
    return (u16)((u + 0x7FFFu + ((u >> 16) & 1u)) >> 16);  // RNE
}

__device__ __forceinline__ void gll16(const void* g, void* l) {
    __builtin_amdgcn_global_load_lds(
        (const __attribute__((address_space(1))) unsigned int*)g,
        (__attribute__((address_space(3))) unsigned int*)l, 16, 0, 0);
}

// ---------- kernel 1: PONO center + L2 normalize + transposed bf16 write ----------
// grid: 256 blocks (b = blk>>6, 64 pixels each), 256 threads
__global__ __launch_bounds__(256) void prep_kernel(
    const float* __restrict__ X, const float* __restrict__ Y,
    u16* __restrict__ XnT, u16* __restrict__ YnT)
{
    const int b  = blockIdx.x >> 6;
    const int p0 = (blockIdx.x & 63) << 6;
    const int t  = threadIdx.x;
    const int w  = t >> 6;     // channel quarter (wave id)
    const int ln = t & 63;     // pixel
    const size_t base = (size_t)b * 256 * 4096;

    __shared__ float part[8][64];
    __shared__ float meanL[64], rxL[64], ryL[64];
    __shared__ u16 TX[64][72], TY[64][72];  // [px][64 ch + pad], 16B-aligned rows

    // pass 1: mean over channels of Y (coalesced: lane = pixel)
    float sy = 0.f;
    #pragma unroll 4
    for (int k = 0; k < 64; ++k)
        sy += Y[base + (size_t)(w * 64 + k) * 4096 + p0 + ln];
    part[w][ln] = sy;
    __syncthreads();
    const float mean =
        (part[0][ln] + part[1][ln] + part[2][ln] + part[3][ln]) * (1.f / 256.f);
    __syncthreads();

    // pass 2: centered sum-of-squares for X and Y
    float ssx = 0.f, ssy = 0.f;
    #pragma unroll 4
    for (int k = 0; k < 64; ++k) {
        size_t off = base + (size_t)(w * 64 + k) * 4096 + p0 + ln;
        float dx = X[off] - mean; ssx += dx * dx;
        float dy = Y[off] - mean; ssy += dy * dy;
    }
    part[w][ln] = ssx;
    part[4 + w][ln] = ssy;
    __syncthreads();
    if (w == 0) {
        float sx = part[0][ln] + part[1][ln] + part[2][ln] + part[3][ln];
        float sy2 = part[4][ln] + part[5][ln] + part[6][ln] + part[7][ln];
        meanL[ln] = mean;
        rxL[ln] = 1.f / (sqrtf(sx) + EPSF);
        ryL[ln] = 1.f / (sqrtf(sy2) + EPSF);
    }
    __syncthreads();

    // pass 3: LDS transpose, 4 chunks of 64 channels.
    // load phase: lane = pixel (coalesced fp32), write [px][c] to LDS as bf16
    // store phase: ds_read_b128 of 8 consecutive channels, 16B global stores
    const int cq = t >> 6;               // channel sixteenth within chunk
    const float m = meanL[ln], rxv = rxL[ln], ryv = ryL[ln];
    const int c8 = t & 7, pr = t >> 3;   // store-phase coords
    #pragma unroll
    for (int cb = 0; cb < 4; ++cb) {
        #pragma unroll 4
        for (int k = 0; k < 16; ++k) {
            int c = cb * 64 + cq * 16 + k;
            size_t off = base + (size_t)c * 4096 + p0 + ln;
            TX[ln][cq * 16 + k] = f2bf((X[off] - m) * rxv);
            TY[ln][cq * 16 + k] = f2bf((Y[off] - m) * ryv);
        }
        __syncthreads();
        #pragma unroll
        for (int h = 0; h < 2; ++h) {
            int p = h * 32 + pr;
            size_t ob = ((size_t)b * 4096 + p0 + p) * 256 + cb * 64 + c8 * 8;
            *(short8*)(XnT + ob) = *(const short8*)&TX[p][c8 * 8];
            *(short8*)(YnT + ob) = *(const short8*)&TY[p][c8 * 8];
        }
        __syncthreads();
    }
}

// ---------- kernels 2/3: fused GEMM + rowmax (PASS=0) / rowsum-exp (PASS=1) ----------
// tile 128x128, BK=64, 4 waves (2x2), 16x16x32 bf16 MFMA, m97-style staging.
// Epilogue writes per-(row, jt, wavecol) partials — NO global atomics.
template <int PASS>
__global__ __launch_bounds__(256) void cx_pass(
    const u16* __restrict__ XnT, const u16* __restrict__ YnT,
    const float* __restrict__ smax, float* __restrict__ partials)
{
    __shared__ u16 As[128 * 64];   // 16 KB, XOR-swizzled rows
    __shared__ u16 Bs[128 * 64];
    __shared__ float smx[128];

    const int t = threadIdx.x;
    const int w = t >> 6;
    const int l = t & 63;

    // XCD-aware swizzle: batch b -> XCDs {2b, 2b+1}; operands (4MB bf16) L2-fit
    const int id   = blockIdx.x;
    const int xcd  = id & 7;
    const int slot = id >> 3;                 // 0..511
    const int b    = xcd >> 1;
    const int tile = ((xcd & 1) << 9) | slot; // 0..1023
    const int it = tile >> 5, jt = tile & 31;
    const int i0 = it << 7, j0 = jt << 7;

    const u16* Ab = XnT + ((size_t)b * 4096 + i0) * 256;
    const u16* Bb = YnT + ((size_t)b * 4096 + j0) * 256;

    if (PASS == 1 && t < 128)
        smx[t] = smax[(size_t)b * 4096 + i0 + t];

    const int wr = w >> 1, wc = w & 1;
    const int l8 = l & 7, ld8 = l >> 3;
    const int srcChunk = (l8 ^ ld8) << 3;  // inverse-swizzled source chunk (elems)

    f32x4 acc[4][4] = {};

    #pragma unroll
    for (int kt = 0; kt < 4; ++kt) {
        // stage A,B tiles: 4 waves x 4 chunks x 1KB each, linear LDS dest,
        // pre-swizzled global source (involution: chunk ^ (row&7))
        #pragma unroll
        for (int q = 0; q < 4; ++q) {
            const int rbase = (w * 4 + q) * 8;
            const int row = rbase + ld8;
            gll16(Ab + (size_t)row * 256 + kt * 64 + srcChunk, &As[rbase * 64]);
            gll16(Bb + (size_t)row * 256 + kt * 64 + srcChunk, &Bs[rbase * 64]);
        }
        __syncthreads();
        #pragma unroll
        for (int ks = 0; ks < 2; ++ks) {
            const int kb = (ks * 32 + (l >> 4) * 8) * 2;  // frag byte offset in row
            bf16x8 av[4], bv[4];
            #pragma unroll
            for (int f = 0; f < 4; ++f) {
                int ra = wr * 64 + f * 16 + (l & 15);
                av[f] = *(const bf16x8*)((const char*)As + ra * 128 + (kb ^ ((ra & 7) << 4)));
                int rb = wc * 64 + f * 16 + (l & 15);
                bv[f] = *(const bf16x8*)((const char*)Bs + rb * 128 + (kb ^ ((rb & 7) << 4)));
            }
            #pragma unroll
            for (int fr = 0; fr < 4; ++fr)
                #pragma unroll
                for (int fc = 0; fc < 4; ++fc)
                    acc[fr][fc] = __builtin_amdgcn_mfma_f32_16x16x32_bf16(
                        av[fr], bv[fc], acc[fr][fc], 0, 0, 0);
        }
        __syncthreads();
    }

    // epilogue: C/D map col=l&15, row=(l>>4)*4+r (verified m89/m91)
    const int g = l >> 4;
    #pragma unroll
    for (int fr = 0; fr < 4; ++fr) {
        #pragma unroll
        for (int r = 0; r < 4; ++r) {
            const int row = wr * 64 + fr * 16 + g * 4 + r;
            if (PASS == 0) {
                float m = fmaxf(fmaxf(acc[fr][0][r], acc[fr][1][r]),
                                fmaxf(acc[fr][2][r], acc[fr][3][r]));
                m = fmaxf(m, __shfl_xor(m, 1, 64));
                m = fmaxf(m, __shfl_xor(m, 2, 64));
                m = fmaxf(m, __shfl_xor(m, 4, 64));
                m = fmaxf(m, __shfl_xor(m, 8, 64));
                if ((l & 15) == 0)
                    partials[((size_t)b * 4096 + i0 + row) * 64 + jt * 2 + wc] = m;
            } else {
                float mrow = smx[row];
                float itau = 1.0f / (0.1f * (1.001f - mrow));
                float s = __expf((acc[fr][0][r] - mrow) * itau)
                        + __expf((acc[fr][1][r] - mrow) * itau)
                        + __expf((acc[fr][2][r] - mrow) * itau)
                        + __expf((acc[fr][3][r] - mrow) * itau);
                s += __shfl_xor(s, 1, 64);
                s += __shfl_xor(s, 2, 64);
                s += __shfl_xor(s, 4, 64);
                s += __shfl_xor(s, 8, 64);
                if ((l & 15) == 0)
                    partials[((size_t)b * 4096 + i0 + row) * 64 + jt * 2 + wc] = s;
            }
        }
    }
}

// ---------- row reductions over the 64 partial slots ----------
template <int OP>  // 0 = max, 1 = sum
__global__ __launch_bounds__(256) void reduce_rows(
    const float* __restrict__ part, float* __restrict__ outv)
{
    const int row = blockIdx.x * 256 + threadIdx.x;
    const float4* p = (const float4*)(part + (size_t)row * 64);
    float a = (OP == 0) ? -2.0f : 0.0f;
    #pragma unroll 4
    for (int k = 0; k < 16; ++k) {
        float4 v = p[k];
        if (OP == 0)
            a = fmaxf(a, fmaxf(fmaxf(v.x, v.y), fmaxf(v.z, v.w)));
        else
            a += (v.x + v.y) + (v.z + v.w);
    }
    outv[row] = a;
}

// ---------- final reduction ----------
__global__ __launch_bounds__(256) void final_kernel(
    const float* __restrict__ Stot, float* __restrict__ out)
{
    __shared__ float red[4];
    const int t = threadIdx.x;
    float loss = 0.f;
    for (int b = 0; b < 4; ++b) {
        float s = 0.f;
        for (int i = t; i < 4096; i += 256)
            s += 1.0f / Stot[(size_t)b * 4096 + i];
        #pragma unroll
        for (int d = 1; d <= 32; d <<= 1) s += __shfl_xor(s, d, 64);
        if ((t & 63) == 0) red[t >> 6] = s;
        __syncthreads();
        if (t == 0) {
            float tot = red[0] + red[1] + red[2] + red[3];
            loss += -logf(tot * (1.f / 4096.f));
        }
        __syncthreads();
    }
    if (t == 0) out[0] = loss * 0.25f;
}

extern "C" void kernel_launch(void* const* d_in, const int* in_sizes, int n_in,
                              void* d_out, int out_size, void* d_ws, size_t ws_size,
                              hipStream_t stream)
{
    const float* X = (const float*)d_in[0];
    const float* Y = (const float*)d_in[1];
    char* ws = (char*)d_ws;
    u16* XnT = (u16*)(ws);                                   // 8 MB
    u16* YnT = (u16*)(ws + (8u << 20));                      // 8 MB
    float* partials = (float*)(ws + (16u << 20));            // 4 MB [16384][64]
    float* smax = (float*)(ws + (20u << 20));                // 64 KB
    float* Stot = (float*)(ws + (20u << 20) + (64u << 10));  // 64 KB
    float* out = (float*)d_out;

    hipLaunchKernelGGL(prep_kernel, dim3(256), dim3(256), 0, stream,
                       X, Y, XnT, YnT);
    hipLaunchKernelGGL((cx_pass<0>), dim3(4096), dim3(256), 0, stream,
                       XnT, YnT, smax, partials);
    hipLaunchKernelGGL((reduce_rows<0>), dim3(64), dim3(256), 0, stream,
                       partials, smax);
    hipLaunchKernelGGL((cx_pass<1>), dim3(4096), dim3(256), 0, stream,
                       XnT, YnT, smax, partials);
    hipLaunchKernelGGL((reduce_rows<1>), dim3(64), dim3(256), 0, stream,
                       partials, Stot);
    hipLaunchKernelGGL(final_kernel, dim3(1), dim3(256), 0, stream, Stot, out);
}

// Round 3
// 200.512 us; speedup vs baseline: 1.4495x; 1.0976x over previous
//
#include <hip/hip_runtime.h>
#include <hip/hip_bf16.h>

typedef unsigned short u16;
typedef unsigned int u32;
typedef __attribute__((ext_vector_type(8))) __bf16 bf16x8;
typedef __attribute__((ext_vector_type(4))) float f32x4;
typedef __attribute__((ext_vector_type(8))) short short8;

#define EPSF 2.220446049250313e-16f

__device__ __forceinline__ u16 f2bf(float f) {
    u32 u = __float_as_uint(f);
    return (u16)((u + 0x7FFFu + ((u >> 16) & 1u)) >> 16);  // RNE
}

__device__ __forceinline__ void gll16(const void* g, void* l) {
    __builtin_amdgcn_global_load_lds(
        (const __attribute__((address_space(1))) unsigned int*)g,
        (__attribute__((address_space(3))) unsigned int*)l, 16, 0, 0);
}

#define MEMFENCE asm volatile("" ::: "memory")
#define BAR() do { MEMFENCE; __builtin_amdgcn_s_barrier(); MEMFENCE; } while (0)
#define VMWAIT(N) do { asm volatile("s_waitcnt vmcnt(" #N ")" ::: "memory"); \
                       __builtin_amdgcn_sched_barrier(0); } while (0)

// ---------- kernel 1: PONO center + L2 normalize + transposed bf16 write ----------
// single pass over X,Y: stats via sums (ss = Sxx - 2m*Sx + 256m^2), fp32 LDS
// retention for the transpose. grid 512 (b = blk>>7, 32 px each), 512 threads.
__global__ __launch_bounds__(512) void prep_kernel(
    const float* __restrict__ X, const float* __restrict__ Y,
    u16* __restrict__ XnT, u16* __restrict__ YnT)
{
    const int b  = blockIdx.x >> 7;
    const int p0 = (blockIdx.x & 127) << 5;
    const int t  = threadIdx.x;
    const int w  = t >> 6, l = t & 63;
    const size_t base = (size_t)b * 256 * 4096 + p0;

    __shared__ float TXf[32][260], TYf[32][260];  // pad 260: 16B-aligned rows
    __shared__ float part[8][16][8];
    __shared__ float meanL[32], rxL[32], ryL[32];

    const int pxp = t & 15;   // pixel pair: px = 2*pxp, 2*pxp+1
    const int cs  = t >> 4;   // 0..31 -> channels cs*8 .. cs*8+7
    float sx0=0,sxx0=0,sy0=0,syy0=0, sx1=0,sxx1=0,sy1=0,syy1=0;
    #pragma unroll
    for (int k = 0; k < 8; ++k) {
        int c = cs * 8 + k;
        size_t off = base + (size_t)c * 4096 + pxp * 2;
        float2 vx = *(const float2*)(X + off);
        float2 vy = *(const float2*)(Y + off);
        TXf[pxp*2][c] = vx.x; TXf[pxp*2+1][c] = vx.y;
        TYf[pxp*2][c] = vy.x; TYf[pxp*2+1][c] = vy.y;
        sx0 += vx.x; sxx0 += vx.x*vx.x; sy0 += vy.x; syy0 += vy.x*vy.x;
        sx1 += vx.y; sxx1 += vx.y*vx.y; sy1 += vy.y; syy1 += vy.y*vy.y;
    }
    // reduce over cs within wave (xor 16 flips cs&1, xor 32 flips cs&2)
    #pragma unroll
    for (int sh = 16; sh <= 32; sh <<= 1) {
        sx0 += __shfl_xor(sx0, sh, 64); sxx0 += __shfl_xor(sxx0, sh, 64);
        sy0 += __shfl_xor(sy0, sh, 64); syy0 += __shfl_xor(syy0, sh, 64);
        sx1 += __shfl_xor(sx1, sh, 64); sxx1 += __shfl_xor(sxx1, sh, 64);
        sy1 += __shfl_xor(sy1, sh, 64); syy1 += __shfl_xor(syy1, sh, 64);
    }
    if (l < 16) {
        part[w][l][0]=sx0; part[w][l][1]=sxx0; part[w][l][2]=sy0; part[w][l][3]=syy0;
        part[w][l][4]=sx1; part[w][l][5]=sxx1; part[w][l][6]=sy1; part[w][l][7]=syy1;
    }
    __syncthreads();
    if (t < 32) {
        const int pp = t >> 1, sub = (t & 1) * 4;
        float Sx=0, Sxx=0, Sy=0, Syy=0;
        #pragma unroll
        for (int ww = 0; ww < 8; ++ww) {
            Sx += part[ww][pp][sub+0]; Sxx += part[ww][pp][sub+1];
            Sy += part[ww][pp][sub+2]; Syy += part[ww][pp][sub+3];
        }
        float m = Sy * (1.f / 256.f);
        float ssx = fmaxf(Sxx - 2.f*m*Sx + 256.f*m*m, 0.f);
        float ssy = fmaxf(Syy - 2.f*m*Sy + 256.f*m*m, 0.f);
        meanL[t] = m;
        rxL[t] = 1.f / (sqrtf(ssx) + EPSF);
        ryL[t] = 1.f / (sqrtf(ssy) + EPSF);
    }
    __syncthreads();
    // store phase: thread (c16 = t&15, px = t>>4): 16 ch, 2x short8 stores
    {
        const int c16 = t & 15, px = t >> 4;
        const float m = meanL[px], rxv = rxL[px], ryv = ryL[px];
        size_t ob = ((size_t)b * 4096 + p0 + px) * 256 + c16 * 16;
        #pragma unroll
        for (int h = 0; h < 2; ++h) {
            short8 hx, hy;
            #pragma unroll
            for (int k = 0; k < 8; ++k) {
                int c = c16 * 16 + h * 8 + k;
                hx[k] = (short)f2bf((TXf[px][c] - m) * rxv);
                hy[k] = (short)f2bf((TYf[px][c] - m) * ryv);
            }
            *(short8*)(XnT + ob + h * 8) = hx;
            *(short8*)(YnT + ob + h * 8) = hy;
        }
    }
}

// ---------- kernels 2/3: 256^2-tile fused GEMM, 8-phase counted-vmcnt pipeline ----
// 8 waves (2M x 4N), BK=64, K=256 -> 4 K-tiles, static 16-phase schedule.
// LDS: As/Bs [dbuf][half(128 rows)][128*64] u16, XOR-swizzled rows.
template <int PASS>
__global__ __launch_bounds__(512, 2) void cx_pass(
    const u16* __restrict__ XnT, const u16* __restrict__ YnT,
    const float* __restrict__ smax, float* __restrict__ partials)
{
    __shared__ u16 As[2][2][128 * 64];   // 64 KB
    __shared__ u16 Bs[2][2][128 * 64];   // 64 KB
    __shared__ float red[256][4];        // 4 KB
    __shared__ float smx[256];           // 1 KB

    const int t = threadIdx.x;
    const int w = t >> 6;
    const int l = t & 63;
    const int wr  = w >> 2;   // 0..1 M-half
    const int wcn = w & 3;    // 0..3 N-quarter

    // XCD swizzle: batch b pinned to XCD pair {2b, 2b+1}
    const int id   = blockIdx.x;
    const int xcd  = id & 7;
    const int slot = id >> 3;                 // 0..127
    const int b    = xcd >> 1;
    const int tile = ((xcd & 1) << 7) | slot; // 0..255
    const int it = tile >> 4, jt = tile & 15;
    const int i0 = it << 8, j0 = jt << 8;

    const u16* Ab = XnT + ((size_t)b * 4096 + i0) * 256;
    const u16* Bb = YnT + ((size_t)b * 4096 + j0) * 256;

    if (PASS == 1 && t < 256)
        smx[t] = smax[(size_t)b * 4096 + i0 + t];

    // staging geometry: per gll16, 512 thr x 16B cover 64 rows x 64 elems
    const int srow = t >> 3;                               // 0..63
    const int sOff = srow * 256 + (((t & 7) ^ (srow & 7)) << 3);  // pre-swizzled src

    auto stageA = [&](int d, int h, int kt) {
        gll16(Ab + h * 32768 +         kt * 64 + sOff, &As[d][h][w * 512]);
        gll16(Ab + h * 32768 + 16384 + kt * 64 + sOff, &As[d][h][4096 + w * 512]);
    };
    auto stageB = [&](int d, int h, int kt) {
        gll16(Bb + h * 32768 +         kt * 64 + sOff, &Bs[d][h][w * 512]);
        gll16(Bb + h * 32768 + 16384 + kt * 64 + sOff, &Bs[d][h][4096 + w * 512]);
    };

    bf16x8 a[4][2], b0[2][2], b1[2][2];
    f32x4 acc[8][4] = {};

    const int l15 = l & 15;
    const int kbh = (l >> 4) << 4;  // hi-K byte offset within 128B row

    auto readA = [&](int d, int mh) {
        const char* basep = (const char*)&As[d][wr][0];
        #pragma unroll
        for (int fm = 0; fm < 4; ++fm)
            #pragma unroll
            for (int ks = 0; ks < 2; ++ks) {
                int row = mh * 64 + fm * 16 + l15;
                int kb = ks * 64 + kbh;
                a[fm][ks] = *(const bf16x8*)(basep + row * 128 + (kb ^ ((row & 7) << 4)));
            }
    };
    auto readB = [&](int d, int nh, bf16x8 (&bb)[2][2]) {
        const char* basep = (const char*)&Bs[d][wcn >> 1][0];
        #pragma unroll
        for (int fp = 0; fp < 2; ++fp)
            #pragma unroll
            for (int ks = 0; ks < 2; ++ks) {
                int row = (wcn & 1) * 64 + (nh * 2 + fp) * 16 + l15;
                int kb = ks * 64 + kbh;
                bb[fp][ks] = *(const bf16x8*)(basep + row * 128 + (kb ^ ((row & 7) << 4)));
            }
    };
    auto mmaQ = [&](int mh, int nh, bf16x8 (&bb)[2][2]) {
        __builtin_amdgcn_s_setprio(1);
        #pragma unroll
        for (int fm = 0; fm < 4; ++fm)
            #pragma unroll
            for (int fp = 0; fp < 2; ++fp)
                #pragma unroll
                for (int ks = 0; ks < 2; ++ks)
                    acc[mh*4+fm][nh*2+fp] = __builtin_amdgcn_mfma_f32_16x16x32_bf16(
                        a[fm][ks], bb[fp][ks], acc[mh*4+fm][nh*2+fp], 0, 0, 0);
        __builtin_amdgcn_s_setprio(0);
    };

    // prologue: kt0 -> buf0, kt1 -> buf1 (program order fixed for vmcnt math)
    stageA(0,0,0); stageA(0,1,0); stageB(0,0,0); stageB(0,1,0);
    stageA(1,0,1); stageA(1,1,1); stageB(1,0,1); stageB(1,1,1);

    // ---- iter0: kt0 (buf0) p1-4, kt1 (buf1) p5-8 ----
    VMWAIT(8); BAR();                       // kt0 landed (kt1's 8 may be in flight)
    readA(0,0); readB(0,0,b0);  BAR(); mmaQ(0,0,b0);            // p1
    readB(0,1,b1);              BAR(); mmaQ(0,1,b1);            // p2
    readA(0,1);                 BAR(); mmaQ(1,1,b1);            // p3
    stageB(0,0,2);              BAR(); mmaQ(1,0,b0);            // p4
    VMWAIT(2); BAR();                       // kt1 landed
    readA(1,0); readB(1,0,b0); stageB(0,1,2); BAR(); mmaQ(0,0,b0);  // p5
    readB(1,1,b1);             stageA(0,0,2); BAR(); mmaQ(0,1,b1);  // p6
    readA(1,1);                stageA(0,1,2); BAR(); mmaQ(1,1,b1);  // p7
    stageB(1,0,3);                            BAR(); mmaQ(1,0,b0);  // p8
    // ---- iter1: kt2 (buf0) p1-4, kt3 (buf1) p5-8 ----
    VMWAIT(2); BAR();                       // kt2 landed (p8's 2 may be in flight)
    readA(0,0); readB(0,0,b0); stageB(1,1,3); BAR(); mmaQ(0,0,b0);  // p1
    readB(0,1,b1);             stageA(1,0,3); BAR(); mmaQ(0,1,b1);  // p2
    readA(0,1);                stageA(1,1,3); BAR(); mmaQ(1,1,b1);  // p3
    BAR(); mmaQ(1,0,b0);                                            // p4
    VMWAIT(0); BAR();                       // kt3 landed
    readA(1,0); readB(1,0,b0);  BAR(); mmaQ(0,0,b0);            // p5
    readB(1,1,b1);              BAR(); mmaQ(0,1,b1);            // p6
    readA(1,1);                 BAR(); mmaQ(1,1,b1);            // p7
    BAR(); mmaQ(1,0,b0);                                        // p8

    // ---- epilogue: row reduce -> red[256][4], then per-row combine ----
    const int g = l >> 4;
    #pragma unroll
    for (int fm = 0; fm < 8; ++fm) {
        #pragma unroll
        for (int r = 0; r < 4; ++r) {
            const int rowL = wr * 128 + fm * 16 + g * 4 + r;
            float v;
            if (PASS == 0) {
                v = fmaxf(fmaxf(acc[fm][0][r], acc[fm][1][r]),
                          fmaxf(acc[fm][2][r], acc[fm][3][r]));
                v = fmaxf(v, __shfl_xor(v, 1, 64));
                v = fmaxf(v, __shfl_xor(v, 2, 64));
                v = fmaxf(v, __shfl_xor(v, 4, 64));
                v = fmaxf(v, __shfl_xor(v, 8, 64));
            } else {
                float mrow = smx[rowL];
                float itau = 1.0f / (0.1f * (1.001f - mrow));
                v = __expf((acc[fm][0][r] - mrow) * itau)
                  + __expf((acc[fm][1][r] - mrow) * itau)
                  + __expf((acc[fm][2][r] - mrow) * itau)
                  + __expf((acc[fm][3][r] - mrow) * itau);
                v += __shfl_xor(v, 1, 64);
                v += __shfl_xor(v, 2, 64);
                v += __shfl_xor(v, 4, 64);
                v += __shfl_xor(v, 8, 64);
            }
            if (l15 == 0) red[rowL][wcn] = v;
        }
    }
    BAR();
    if (t < 256) {
        float4 vv = *(const float4*)&red[t][0];
        float res = (PASS == 0)
            ? fmaxf(fmaxf(vv.x, vv.y), fmaxf(vv.z, vv.w))
            : (vv.x + vv.y) + (vv.z + vv.w);
        partials[((size_t)b * 4096 + i0 + t) * 16 + jt] = res;
    }
}

// ---------- row reductions over the 16 partial slots ----------
template <int OP>  // 0 = max, 1 = sum
__global__ __launch_bounds__(256) void reduce_rows(
    const float* __restrict__ part, float* __restrict__ outv)
{
    const int row = blockIdx.x * 256 + threadIdx.x;
    const float4* p = (const float4*)(part + (size_t)row * 16);
    float a = (OP == 0) ? -2.0f : 0.0f;
    #pragma unroll
    for (int k = 0; k < 4; ++k) {
        float4 v = p[k];
        if (OP == 0) a = fmaxf(a, fmaxf(fmaxf(v.x, v.y), fmaxf(v.z, v.w)));
        else         a += (v.x + v.y) + (v.z + v.w);
    }
    outv[row] = a;
}

// ---------- final reduction ----------
__global__ __launch_bounds__(1024) void final_kernel(
    const float* __restrict__ Stot, float* __restrict__ out)
{
    __shared__ float red[16];
    const int t = threadIdx.x;
    float loss = 0.f;
    for (int b = 0; b < 4; ++b) {
        float s = 0.f;
        #pragma unroll
        for (int k = 0; k < 4; ++k)
            s += 1.0f / Stot[(size_t)b * 4096 + k * 1024 + t];
        #pragma unroll
        for (int sh = 1; sh <= 32; sh <<= 1) s += __shfl_xor(s, sh, 64);
        if ((t & 63) == 0) red[t >> 6] = s;
        __syncthreads();
        if (t == 0) {
            float tot = 0.f;
            #pragma unroll
            for (int k = 0; k < 16; ++k) tot += red[k];
            loss += -logf(tot * (1.f / 4096.f));
        }
        __syncthreads();
    }
    if (t == 0) out[0] = loss * 0.25f;
}

extern "C" void kernel_launch(void* const* d_in, const int* in_sizes, int n_in,
                              void* d_out, int out_size, void* d_ws, size_t ws_size,
                              hipStream_t stream)
{
    const float* X = (const float*)d_in[0];
    const float* Y = (const float*)d_in[1];
    char* ws = (char*)d_ws;
    u16* XnT = (u16*)(ws);                                   // 8 MB
    u16* YnT = (u16*)(ws + (8u << 20));                      // 8 MB
    float* partials = (float*)(ws + (16u << 20));            // 1 MB [16384][16]
    float* smax = (float*)(ws + (17u << 20));                // 64 KB
    float* Stot = (float*)(ws + (17u << 20) + (64u << 10));  // 64 KB
    float* out = (float*)d_out;

    hipLaunchKernelGGL(prep_kernel, dim3(512), dim3(512), 0, stream,
                       X, Y, XnT, YnT);
    hipLaunchKernelGGL((cx_pass<0>), dim3(1024), dim3(512), 0, stream,
                       XnT, YnT, smax, partials);
    hipLaunchKernelGGL((reduce_rows<0>), dim3(64), dim3(256), 0, stream,
                       partials, smax);
    hipLaunchKernelGGL((cx_pass<1>), dim3(1024), dim3(512), 0, stream,
                       XnT, YnT, smax, partials);
    hipLaunchKernelGGL((reduce_rows<1>), dim3(64), dim3(256), 0, stream,
                       partials, Stot);
    hipLaunchKernelGGL(final_kernel, dim3(1), dim3(1024), 0, stream, Stot, out);
}